// Round 9
// baseline (262.932 us; speedup 1.0000x reference)
//
#include <hip/hip_runtime.h>
#include <hip/hip_bf16.h>
#include <cmath>

#define NB 4
#define NM 32
#define DKc 256
#define DVc 32
#define NP 4096

using bf16x8 = __attribute__((ext_vector_type(8))) short;
using f32x4  = __attribute__((ext_vector_type(4))) float;
using f32x2  = __attribute__((ext_vector_type(2))) float;

__device__ __forceinline__ unsigned short f2bf(float f) {
    union { float f; unsigned u; } x; x.f = f;
    unsigned r = 0x7FFFu + ((x.u >> 16) & 1u);
    return (unsigned short)((x.u + r) >> 16);
}

// wave-uniform pointer -> SGPR (compiler divergence analysis can't prove wave-level
// uniformity of wave-index-derived bases; readfirstlane legalizes the "s" constraint)
__device__ __forceinline__ const float* rfl_ptr(const float* p) {
    unsigned long long u = (unsigned long long)p;
    unsigned lo = __builtin_amdgcn_readfirstlane((unsigned)u);
    unsigned hi = __builtin_amdgcn_readfirstlane((unsigned)(u >> 32));
    return (const float*)(((unsigned long long)hi << 32) | lo);
}

// ---------------- k_prep: fc transpose (1024 blocks) + W transposes (32) + vproj (64) ----------------
__global__ __launch_bounds__(256) void k_prep(
    const float* __restrict__ fc, unsigned short* __restrict__ fcT,
    const float* __restrict__ Q, unsigned short* __restrict__ WTq,
    const float* __restrict__ K, unsigned short* __restrict__ WTk,
    const float* __restrict__ fm, const float* __restrict__ V, float* __restrict__ vproj) {
    int x = blockIdx.x;
    int t = threadIdx.x;
    if (x < 1056) {
        __shared__ float tile[64][65];
        const float* s; unsigned short* d; int R, C, r0, c0;
        if (x < 1024) {
            int bb = x >> 8, rest = x & 255;
            R = 256; C = 4096;
            r0 = (rest >> 6) * 64; c0 = (rest & 63) * 64;
            s = fc + (long)bb * 256 * 4096; d = fcT + (long)bb * 256 * 4096;
        } else {
            int i = x - 1024;
            int mat = i >> 4, idx = i & 15;
            R = 256; C = 256;
            r0 = (idx >> 2) * 64; c0 = (idx & 3) * 64;
            s = mat ? K : Q; d = mat ? WTk : WTq;
        }
        #pragma unroll
        for (int j = 0; j < 16; ++j) {
            int i = t + 256 * j;
            int r = i >> 6, c = i & 63;
            tile[r][c] = s[(long)(r0 + r) * C + c0 + c];
        }
        __syncthreads();
        #pragma unroll
        for (int j = 0; j < 8; ++j) {
            int i = t + 256 * j;
            int row = i >> 5;
            int pr = i & 31;
            float f0 = tile[2 * pr][row];
            float f1 = tile[2 * pr + 1][row];
            unsigned pack = (unsigned)f2bf(f0) | ((unsigned)f2bf(f1) << 16);
            reinterpret_cast<unsigned*>(d)[(((long)(c0 + row) * R + r0) >> 1) + pr] = pack;
        }
    } else {
        __shared__ float Vl[32][32];
        __shared__ float fml[32][256];
        int i = x - 1056;
        int b = i >> 4, p0 = (i & 15) * 256;
        #pragma unroll
        for (int j = 0; j < 4; ++j) { int ii = t + 256 * j; Vl[ii >> 5][ii & 31] = V[ii]; }
        for (int j = 0; j < 32; ++j) {
            int ii = t + 256 * j;
            int dd = ii >> 8, c = ii & 255;
            fml[dd][c] = fm[((long)b * DVc + dd) * NP + p0 + c];
        }
        __syncthreads();
        float acc[32];
        #pragma unroll
        for (int e = 0; e < 32; ++e) acc[e] = 0.f;
        for (int dd = 0; dd < 32; ++dd) {
            float fv = fml[dd][t];
            #pragma unroll
            for (int e = 0; e < 32; ++e) acc[e] += fv * Vl[dd][e];
        }
        #pragma unroll
        for (int e = 0; e < 32; ++e) vproj[((long)b * DVc + e) * NP + p0 + t] = acc[e];
    }
}

// ---------------- k_proj: full-e (256) per 64-p tile. grid (64, 8=b*mat) ----------------
__global__ __launch_bounds__(256) void k_proj(
    const unsigned short* __restrict__ WTq, const unsigned short* __restrict__ WTk,
    const unsigned short* __restrict__ fcT,
    float* __restrict__ qproj, float* __restrict__ kproj) {
    int t = threadIdx.x;
    int wave = t >> 6, lane = t & 63;
    int y = blockIdx.y;
    int b = y & 3, mat = y >> 2;
    int p0 = blockIdx.x * 64;
    int ln = lane & 15, quad = lane >> 4;
    const unsigned short* WT = mat ? WTk : WTq;
    float* dst = mat ? kproj : qproj;
    int e0w = wave * 64;
    const unsigned short* bbase = fcT + ((long)b * NP + p0 + ln) * DKc + quad * 8;
    f32x4 acc[4][4] = {};
    for (int kk = 0; kk < DKc; kk += 32) {
        bf16x8 a[4], bb[4];
        #pragma unroll
        for (int i = 0; i < 4; ++i)
            a[i] = *reinterpret_cast<const bf16x8*>(WT + (long)(e0w + i * 16 + ln) * DKc + quad * 8 + kk);
        #pragma unroll
        for (int j = 0; j < 4; ++j)
            bb[j] = *reinterpret_cast<const bf16x8*>(bbase + (long)j * 16 * DKc + kk);
        #pragma unroll
        for (int i = 0; i < 4; ++i)
            #pragma unroll
            for (int j = 0; j < 4; ++j)
                acc[i][j] = __builtin_amdgcn_mfma_f32_16x16x32_bf16(a[i], bb[j], acc[i][j], 0, 0, 0);
    }
    #pragma unroll
    for (int i = 0; i < 4; ++i)
        #pragma unroll
        for (int j = 0; j < 4; ++j)
            #pragma unroll
            for (int r = 0; r < 4; ++r) {
                int e = e0w + i * 16 + quad * 4 + r, p = p0 + j * 16 + ln;
                dst[((long)b * DKc + e) * NP + p] = acc[i][j][r];
            }
}

// ---------------- k_fused: x4 asm-ring scores + softmax(w) + ctx + epilogue ----------------
// grid 256 (b*64+hrow), 1024 thr, __launch_bounds__(1024,4) -> VGPR cap 128 (no spill;
// round-6's VGPR_Count=48 proved the compiler spilled the ring to scratch).
// Phase 2: wave=(eh,mg), lane=(mi,wg). m=mg*4+mi, w=[wg*4,wg*4+4), e-half=eh.
// Ring: 3 named slots x 8 dwordx4 (4 k + 4 q), 32 hand-unrolled stages,
// counted s_waitcnt vmcnt(16) + sched_barrier(0). 24 KB/wave in flight.
// Bases are wave-uniform (NOT block-uniform) -> must go through rfl_ptr to
// satisfy the "s" constraint (round-8 failure: divergent base -> v[2:3] -> invalid).
#define LD8_I(K0,K1,K2,K3,Q0,Q1,Q2,Q3) asm volatile( \
    "global_load_dwordx4 %0, %8, %10\n\t"  "v_add_u32 %8, 0x4000, %8\n\t" \
    "global_load_dwordx4 %1, %8, %10\n\t"  "v_add_u32 %8, 0x4000, %8\n\t" \
    "global_load_dwordx4 %2, %8, %10\n\t"  "v_add_u32 %8, 0x4000, %8\n\t" \
    "global_load_dwordx4 %3, %8, %10\n\t"  "v_add_u32 %8, 0x4000, %8\n\t" \
    "global_load_dwordx4 %4, %9, %11\n\t"  "v_add_u32 %9, 0x4000, %9\n\t" \
    "global_load_dwordx4 %5, %9, %11\n\t"  "v_add_u32 %9, 0x4000, %9\n\t" \
    "global_load_dwordx4 %6, %9, %11\n\t"  "v_add_u32 %9, 0x4000, %9\n\t" \
    "global_load_dwordx4 %7, %9, %11" \
    : "=&v"(K0), "=&v"(K1), "=&v"(K2), "=&v"(K3), \
      "=&v"(Q0), "=&v"(Q1), "=&v"(Q2), "=&v"(Q3), "+v"(vk), "+v"(vq) \
    : "s"(kb_s), "s"(qb_s) : "memory"); \
    asm volatile("v_add_u32 %0, 0x4000, %0" : "+v"(vq));
#define LD8(...) LD8_I(__VA_ARGS__)

#define W16 do { asm volatile("s_waitcnt vmcnt(16)" ::: "memory"); \
                 __builtin_amdgcn_sched_barrier(0); } while (0)
#define W8  do { asm volatile("s_waitcnt vmcnt(8)"  ::: "memory"); \
                 __builtin_amdgcn_sched_barrier(0); } while (0)
#define W0  do { asm volatile("s_waitcnt vmcnt(0)"  ::: "memory"); \
                 __builtin_amdgcn_sched_barrier(0); } while (0)

#define FMAS_I(K0,K1,K2,K3,Q0,Q1,Q2,Q3) { c4 += Q0*K0; c4 += Q1*K1; c4 += Q2*K2; c4 += Q3*K3; }
#define FMAS(...) FMAS_I(__VA_ARGS__)

#define SLOT_A ka0,ka1,ka2,ka3,qa0,qa1,qa2,qa3
#define SLOT_B kb0,kb1,kb2,kb3,qb0,qb1,qb2,qb3
#define SLOT_C kc0,kc1,kc2,kc3,qc0,qc1,qc2,qc3
#define STEP(SL) W16; FMAS(SL); LD8(SL);

__global__ __launch_bounds__(1024, 4) void k_fused(
    const float* __restrict__ qproj, const float* __restrict__ kproj,
    const float* __restrict__ kbuf, const float* __restrict__ vproj,
    const float* __restrict__ vbuf, const float* __restrict__ fm,
    float* __restrict__ out, float scale) {
    __shared__ float smem[6144];               // 24576 B
    int t = threadIdx.x;
    int b = blockIdx.x >> 6, hrow = blockIdx.x & 63;
    int p0 = hrow * 64;
    int wave = t >> 6, lane = t & 63;
    int wg = lane & 15, mi = lane >> 4;
    const size_t KMS = (size_t)DKc * NP;       // floats per m-slab (4 MB)

    // ---- phase 2: scores ----
    {
        int eh = wave >> 3, mg = wave & 7;
        // wave-uniform bases hoisted to SGPR via readfirstlane; per-lane 32-bit voffsets
        const float* kb_s = rfl_ptr((mg == 0 ? kproj : kbuf + (size_t)(mg * 4 - 4) * KMS)
                                    + (size_t)eh * 128 * NP);
        const float* qb_s = rfl_ptr(qproj + (size_t)b * KMS + (size_t)eh * 128 * NP);
        unsigned vk = (unsigned)(((size_t)mi * KMS + p0 + wg * 4) * 4);
        unsigned vq = (unsigned)((p0 + wg * 4) * 4);

        f32x4 ka0,ka1,ka2,ka3,qa0,qa1,qa2,qa3;
        f32x4 kb0,kb1,kb2,kb3,qb0,qb1,qb2,qb3;
        f32x4 kc0,kc1,kc2,kc3,qc0,qc1,qc2,qc3;
        f32x4 c4 = {0.f, 0.f, 0.f, 0.f};

        LD8(SLOT_A) LD8(SLOT_B) LD8(SLOT_C)    // 24 outstanding
        STEP(SLOT_A) STEP(SLOT_B) STEP(SLOT_C) STEP(SLOT_A) STEP(SLOT_B) STEP(SLOT_C)
        STEP(SLOT_A) STEP(SLOT_B) STEP(SLOT_C) STEP(SLOT_A) STEP(SLOT_B) STEP(SLOT_C)
        STEP(SLOT_A) STEP(SLOT_B) STEP(SLOT_C) STEP(SLOT_A) STEP(SLOT_B) STEP(SLOT_C)
        STEP(SLOT_A) STEP(SLOT_B) STEP(SLOT_C) STEP(SLOT_A) STEP(SLOT_B) STEP(SLOT_C)
        STEP(SLOT_A) STEP(SLOT_B) STEP(SLOT_C) STEP(SLOT_A) STEP(SLOT_B)   // stages 0..28
        W16; FMAS(SLOT_C);                     // stage 29
        W8;  FMAS(SLOT_A);                     // stage 30
        W0;  FMAS(SLOT_B);                     // stage 31
        // partial scores [eh][m][w]: disjoint per wave
        int m = mg * 4 + mi;
        *reinterpret_cast<f32x4*>(&smem[eh * 2048 + m * 64 + wg * 4]) = c4;
    }
    __syncthreads();

    // softmax over w: wave handles rows {2*wave, 2*wave+1}; lane = w
    float att0, att1;
    #pragma unroll
    for (int r = 0; r < 2; ++r) {
        int m = wave * 2 + r;
        float x = (smem[m * 64 + lane] + smem[2048 + m * 64 + lane]) * scale;
        float mx = x;
        #pragma unroll
        for (int d = 1; d < 64; d <<= 1) mx = fmaxf(mx, __shfl_xor(mx, d));
        float ev = __expf(x - mx);
        float sum = ev;
        #pragma unroll
        for (int d = 1; d < 64; d <<= 1) sum += __shfl_xor(sum, d);
        if (r == 0) att0 = ev / sum; else att1 = ev / sum;
    }
    __syncthreads();                           // all partial reads done
    smem[(wave * 2) * 64 + lane] = att0;       // attn[m][w] at [0,2048)
    smem[(wave * 2 + 1) * 64 + lane] = att1;
    __syncthreads();

    // phase 3: ctx. wave=(mh=wave>>3, dq=wave&7); lane=(di=lane>>4, wg).
    {
        int di = lane >> 4;
        int mh = wave >> 3, dq = wave & 7;
        int dd = dq * 4 + di;
        f32x4 c4 = {0.f, 0.f, 0.f, 0.f};
        #pragma unroll
        for (int mm = 0; mm < 16; ++mm) {
            int m = mh * 16 + mm;
            const float* vb_ = (m < 4 ? vproj + (long)m * DVc * NP
                                      : vbuf + (long)(m - 4) * DVc * NP);
            f32x4 a4 = *reinterpret_cast<const f32x4*>(&smem[m * 64 + wg * 4]);
            f32x4 v4 = *reinterpret_cast<const f32x4*>(vb_ + (long)dd * NP + p0 + wg * 4);
            c4 += a4 * v4;
        }
        *reinterpret_cast<f32x4*>(&smem[2048 + mh * 2048 + dd * 64 + wg * 4]) = c4;
    }
    __syncthreads();

    // final: 2048 outputs / 1024 threads
    #pragma unroll
    for (int r = 0; r < 2; ++r) {
        int i = t + 1024 * r;
        int dd2 = i >> 6, w2 = i & 63;
        float c = smem[2048 + dd2 * 64 + w2] + smem[4096 + dd2 * 64 + w2];
        long gi = ((long)b * DVc + dd2) * NP + p0 + w2;
        out[gi] = fm[gi] + 0.5f * c;
    }
}

extern "C" void kernel_launch(void* const* d_in, const int* in_sizes, int n_in,
                              void* d_out, int out_size, void* d_ws, size_t ws_size,
                              hipStream_t stream) {
    const float* fc = (const float*)d_in[0];
    const float* fm = (const float*)d_in[1];
    const float* kb = (const float*)d_in[2];
    const float* vb = (const float*)d_in[3];
    const float* Q  = (const float*)d_in[4];
    const float* K  = (const float*)d_in[5];
    const float* V  = (const float*)d_in[6];
    float* out = (float*)d_out;
    char* ws = (char*)d_ws;
    // layout: qproj/kproj/vproj persistent; fcT+WT dead after k_proj.
    float*          qproj = (float*)(ws);                          // 16777216 B
    float*          kproj = (float*)(ws + 16777216);               // 16777216 B
    float*          vproj = (float*)(ws + 33554432);               //  2097152 B
    unsigned short* fcT   = (unsigned short*)(ws + 35651584);      //  8388608 B
    unsigned short* WTq   = (unsigned short*)(ws + 44040192);      //   131072 B
    unsigned short* WTk   = (unsigned short*)(ws + 44171264);      //   131072 B
    float scale = (float)(log(135168.0) / log(1000.0) / 16.0);

    hipLaunchKernelGGL(k_prep, dim3(1120), dim3(256), 0, stream,
                       fc, fcT, Q, WTq, K, WTk, fm, V, vproj);
    hipLaunchKernelGGL(k_proj, dim3(64, 8), dim3(256), 0, stream,
                       WTq, WTk, fcT, qproj, kproj);
    hipLaunchKernelGGL(k_fused, dim3(256), dim3(1024), 0, stream,
                       qproj, kproj, kb, vproj, vb, fm, out, scale);
}

// Round 11
// 238.211 us; speedup vs baseline: 1.1038x; 1.1038x over previous
//
#include <hip/hip_runtime.h>
#include <hip/hip_bf16.h>
#include <cmath>

#define NB 4
#define NM 32
#define DKc 256
#define DVc 32
#define NP 4096

using bf16x8 = __attribute__((ext_vector_type(8))) short;
using f32x4  = __attribute__((ext_vector_type(4))) float;
using f32x2  = __attribute__((ext_vector_type(2))) float;

__device__ __forceinline__ unsigned short f2bf(float f) {
    union { float f; unsigned u; } x; x.f = f;
    unsigned r = 0x7FFFu + ((x.u >> 16) & 1u);
    return (unsigned short)((x.u + r) >> 16);
}

// async global->LDS DMA, 16 B per lane. No dest VGPR -> compiler cannot collapse
// the batch (rounds 4-9 post-mortem: every VGPR-returning load scheme serialized).
// LDS dest: wave-uniform base + lane*16. Global src: per-lane.
// NOTE round-10 fix: pointer conversion must be an ADDRSPACECAST (aperture-aware),
// NOT an int truncation of the generic address — truncation can yield a garbage
// LDS offset -> out-of-allocation DMA write -> memory violation -> container death.
typedef const unsigned int __attribute__((address_space(1)))* gas1_t;
typedef unsigned int __attribute__((address_space(3)))* las3_t;
__device__ __forceinline__ void glds16(const float* g, float* l) {
    __builtin_amdgcn_global_load_lds((gas1_t)(const unsigned int*)g,
                                     (las3_t)(unsigned int*)l,
                                     16, 0, 0);
}

// ---------------- k_prep: fc transpose (1024 blocks) + W transposes (32) + vproj (64) ----------------
__global__ __launch_bounds__(256) void k_prep(
    const float* __restrict__ fc, unsigned short* __restrict__ fcT,
    const float* __restrict__ Q, unsigned short* __restrict__ WTq,
    const float* __restrict__ K, unsigned short* __restrict__ WTk,
    const float* __restrict__ fm, const float* __restrict__ V, float* __restrict__ vproj) {
    int x = blockIdx.x;
    int t = threadIdx.x;
    if (x < 1056) {
        __shared__ float tile[64][65];
        const float* s; unsigned short* d; int R, C, r0, c0;
        if (x < 1024) {
            int bb = x >> 8, rest = x & 255;
            R = 256; C = 4096;
            r0 = (rest >> 6) * 64; c0 = (rest & 63) * 64;
            s = fc + (long)bb * 256 * 4096; d = fcT + (long)bb * 256 * 4096;
        } else {
            int i = x - 1024;
            int mat = i >> 4, idx = i & 15;
            R = 256; C = 256;
            r0 = (idx >> 2) * 64; c0 = (idx & 3) * 64;
            s = mat ? K : Q; d = mat ? WTk : WTq;
        }
        #pragma unroll
        for (int j = 0; j < 16; ++j) {
            int i = t + 256 * j;
            int r = i >> 6, c = i & 63;
            tile[r][c] = s[(long)(r0 + r) * C + c0 + c];
        }
        __syncthreads();
        #pragma unroll
        for (int j = 0; j < 8; ++j) {
            int i = t + 256 * j;
            int row = i >> 5;
            int pr = i & 31;
            float f0 = tile[2 * pr][row];
            float f1 = tile[2 * pr + 1][row];
            unsigned pack = (unsigned)f2bf(f0) | ((unsigned)f2bf(f1) << 16);
            reinterpret_cast<unsigned*>(d)[(((long)(c0 + row) * R + r0) >> 1) + pr] = pack;
        }
    } else {
        __shared__ float Vl[32][32];
        __shared__ float fml[32][256];
        int i = x - 1056;
        int b = i >> 4, p0 = (i & 15) * 256;
        #pragma unroll
        for (int j = 0; j < 4; ++j) { int ii = t + 256 * j; Vl[ii >> 5][ii & 31] = V[ii]; }
        for (int j = 0; j < 32; ++j) {
            int ii = t + 256 * j;
            int dd = ii >> 8, c = ii & 255;
            fml[dd][c] = fm[((long)b * DVc + dd) * NP + p0 + c];
        }
        __syncthreads();
        float acc[32];
        #pragma unroll
        for (int e = 0; e < 32; ++e) acc[e] = 0.f;
        for (int dd = 0; dd < 32; ++dd) {
            float fv = fml[dd][t];
            #pragma unroll
            for (int e = 0; e < 32; ++e) acc[e] += fv * Vl[dd][e];
        }
        #pragma unroll
        for (int e = 0; e < 32; ++e) vproj[((long)b * DVc + e) * NP + p0 + t] = acc[e];
    }
}

// ---------------- k_proj: full-e (256) per 64-p tile. grid (64, 8=b*mat) ----------------
__global__ __launch_bounds__(256) void k_proj(
    const unsigned short* __restrict__ WTq, const unsigned short* __restrict__ WTk,
    const unsigned short* __restrict__ fcT,
    float* __restrict__ qproj, float* __restrict__ kproj) {
    int t = threadIdx.x;
    int wave = t >> 6, lane = t & 63;
    int y = blockIdx.y;
    int b = y & 3, mat = y >> 2;
    int p0 = blockIdx.x * 64;
    int ln = lane & 15, quad = lane >> 4;
    const unsigned short* WT = mat ? WTk : WTq;
    float* dst = mat ? kproj : qproj;
    int e0w = wave * 64;
    const unsigned short* bbase = fcT + ((long)b * NP + p0 + ln) * DKc + quad * 8;
    f32x4 acc[4][4] = {};
    for (int kk = 0; kk < DKc; kk += 32) {
        bf16x8 a[4], bb[4];
        #pragma unroll
        for (int i = 0; i < 4; ++i)
            a[i] = *reinterpret_cast<const bf16x8*>(WT + (long)(e0w + i * 16 + ln) * DKc + quad * 8 + kk);
        #pragma unroll
        for (int j = 0; j < 4; ++j)
            bb[j] = *reinterpret_cast<const bf16x8*>(bbase + (long)j * 16 * DKc + kk);
        #pragma unroll
        for (int i = 0; i < 4; ++i)
            #pragma unroll
            for (int j = 0; j < 4; ++j)
                acc[i][j] = __builtin_amdgcn_mfma_f32_16x16x32_bf16(a[i], bb[j], acc[i][j], 0, 0, 0);
    }
    #pragma unroll
    for (int i = 0; i < 4; ++i)
        #pragma unroll
        for (int j = 0; j < 4; ++j)
            #pragma unroll
            for (int r = 0; r < 4; ++r) {
                int e = e0w + i * 16 + quad * 4 + r, p = p0 + j * 16 + ln;
                dst[((long)b * DKc + e) * NP + p] = acc[i][j][r];
            }
}

// ---------------- k_scores: global_load_lds staged, full-e, writes FINAL scores ----------------
// grid (64 wseg, 8 mq), 256 thr (4 waves). Block covers: 64 w x 4 m x 256 e x 4 b.
// Per iter (8 e): wave es DMAs m-row es's 8 e-rows (2 glds16 = 2 KB) into LDS buf,
// double-buffered; computes previous buf (q direct-from-L2, k from LDS); 1 barrier/iter
// (barrier drains vmcnt -> next buf complete; prev buf consumed before overwrite).
// Epilogue: fold 4 e-quarter partials via LDS, write scores[b][m][w] (2 MB total,
// replaces the old 16.8 MB partial round-trip).
__global__ __launch_bounds__(256) void k_scores(
    const float* __restrict__ qproj, const float* __restrict__ kproj,
    const float* __restrict__ kbuf, float* __restrict__ scores) {
    __shared__ float kst[2][2048];   // 2 x 8 KB: [32 rows = m*8+e][64 w]
    __shared__ float red[4096];      // 16 KB: [es][16 bm][64 w]
    int t = threadIdx.x;
    int w = t & 63, es = t >> 6;     // es = wave id (0..3)
    int wseg = blockIdx.x, mq = blockIdx.y;
    int w0 = wseg * 64;
    const size_t KMS = (size_t)DKc * NP;

    // wave es owns m-row m = mq*4 + es for staging
    const float* kslab = (mq == 0 ? kproj + (size_t)es * KMS
                                  : kbuf + (size_t)(mq * 4 + es - 4) * KMS);
    // per-lane src: lane w -> stage row (w>>4) within the 4-row instr, 16B col (w&15)
    const float* g0 = kslab + (size_t)(w >> 4) * NP + w0 + (w & 15) * 4;

    const float* qb = qproj;         // q[b][e][p]
    float acc[4][4];                 // [b][m]
    #pragma unroll
    for (int b = 0; b < 4; ++b)
        #pragma unroll
        for (int m = 0; m < 4; ++m) acc[b][m] = 0.f;

    // prologue: stage iter 0 into buf 0 (lane w lands at float offset es*512 + w*4,
    // which equals [e_loc = w>>4][(w&15)*4] of this wave's 8-row tile — layout matches)
    glds16(g0,            &kst[0][es * 512]);
    glds16(g0 + 4 * NP,   &kst[0][es * 512 + 256]);
    __syncthreads();

    for (int it = 0; it < 32; ++it) {
        int cur = it & 1;
        if (it < 31) {               // stage next iter into the other buf
            const float* gn = g0 + (size_t)(it + 1) * 8 * NP;
            glds16(gn,          &kst[cur ^ 1][es * 512]);
            glds16(gn + 4 * NP, &kst[cur ^ 1][es * 512 + 256]);
        }
        // compute this iter: wave es handles e_loc {es*2, es*2+1}
        int e0g = it * 8 + es * 2;
        float qv[4][2];
        #pragma unroll
        for (int b = 0; b < 4; ++b) {
            const float* qp = qb + ((size_t)(b * DKc) + e0g) * NP + w0 + w;
            qv[b][0] = qp[0];
            qv[b][1] = qp[NP];
        }
        #pragma unroll
        for (int m = 0; m < 4; ++m) {
            float k0 = kst[cur][(m * 8 + es * 2) * 64 + w];
            float k1 = kst[cur][(m * 8 + es * 2 + 1) * 64 + w];
            #pragma unroll
            for (int b = 0; b < 4; ++b)
                acc[b][m] = fmaf(qv[b][0], k0, fmaf(qv[b][1], k1, acc[b][m]));
        }
        __syncthreads();             // drains next-buf DMA; protects cur-buf overwrite
    }

    // fold the 4 es-partials (each covered e stride-8 subsets; sum = full 256-dot)
    #pragma unroll
    for (int b = 0; b < 4; ++b)
        #pragma unroll
        for (int m = 0; m < 4; ++m)
            red[es * 1024 + (b * 4 + m) * 64 + w] = acc[b][m];
    __syncthreads();
    #pragma unroll
    for (int j = 0; j < 4; ++j) {
        int idx = t + 256 * j;       // [0,1024): bm = idx>>6, w2 = idx&63
        float v = red[idx] + red[1024 + idx] + red[2048 + idx] + red[3072 + idx];
        int b = idx >> 8, m = (idx >> 6) & 3, w2 = idx & 63;
        scores[((size_t)b * NM + mq * 4 + m) * NP + w0 + w2] = v;
    }
}

// ---------------- k_out: softmax(w) + ctx + epilogue. grid 256 (b*64+hrow), 512 thr ----------------
__global__ __launch_bounds__(512) void k_out(
    const float* __restrict__ scores, const float* __restrict__ vproj,
    const float* __restrict__ vbuf, const float* __restrict__ fm,
    float* __restrict__ out, float scale) {
    __shared__ float sc[32][68];
    int t = threadIdx.x;
    int b = blockIdx.x >> 6, hrow = blockIdx.x & 63;
    int p0h = hrow * 64;
    int wave = t >> 6, lane = t & 63;
    // load scaled scores: 2048 values / 512 thr
    #pragma unroll
    for (int j = 0; j < 4; ++j) {
        int idx = t + 512 * j;
        int m = idx >> 6, w = idx & 63;
        sc[m][w] = scores[((size_t)b * NM + m) * NP + p0h + w] * scale;
    }
    __syncthreads();
    // softmax over w: each wave handles 4 rows
    #pragma unroll
    for (int r = 0; r < 4; ++r) {
        int m = wave * 4 + r;
        float x = sc[m][lane];
        float mx = x;
        #pragma unroll
        for (int d = 1; d < 64; d <<= 1) mx = fmaxf(mx, __shfl_xor(mx, d));
        float e = __expf(x - mx);
        float sum = e;
        #pragma unroll
        for (int d = 1; d < 64; d <<= 1) sum += __shfl_xor(sum, d);
        sc[m][lane] = e / sum;
    }
    __syncthreads();
    {   // ctx + epilogue: dg = t>>6 (8 groups x 4 d), w = t&63
        int dg = t >> 6, w = t & 63;
        float c4[4] = {0.f, 0.f, 0.f, 0.f};
        #pragma unroll
        for (int m = 0; m < NM; ++m) {
            float a = sc[m][w];
            const float* vp = (m < 4 ? vproj + (long)m * DVc * NP : vbuf + (long)(m - 4) * DVc * NP)
                              + (long)(dg * 4) * NP + p0h + w;
            #pragma unroll
            for (int i = 0; i < 4; ++i) c4[i] += a * vp[(long)i * NP];
        }
        #pragma unroll
        for (int i = 0; i < 4; ++i) {
            long gi = ((long)b * DVc + dg * 4 + i) * NP + p0h + w;
            out[gi] = fm[gi] + 0.5f * c4[i];
        }
    }
}

extern "C" void kernel_launch(void* const* d_in, const int* in_sizes, int n_in,
                              void* d_out, int out_size, void* d_ws, size_t ws_size,
                              hipStream_t stream) {
    const float* fc = (const float*)d_in[0];
    const float* fm = (const float*)d_in[1];
    const float* kb = (const float*)d_in[2];
    const float* vb = (const float*)d_in[3];
    const float* Q  = (const float*)d_in[4];
    const float* K  = (const float*)d_in[5];
    const float* V  = (const float*)d_in[6];
    float* out = (float*)d_out;
    char* ws = (char*)d_ws;
    // layout: qproj/kproj/vproj persistent; fcT+WT dead after k_proj; scores overlays fcT.
    float*          qproj  = (float*)(ws);                          // 16777216 B
    float*          kproj  = (float*)(ws + 16777216);               // 16777216 B
    float*          vproj  = (float*)(ws + 33554432);               //  2097152 B
    unsigned short* fcT    = (unsigned short*)(ws + 35651584);      //  8388608 B
    unsigned short* WTq    = (unsigned short*)(ws + 44040192);      //   131072 B
    unsigned short* WTk    = (unsigned short*)(ws + 44171264);      //   131072 B
    float*          scores = (float*)(ws + 35651584);               //  2097152 B (overlay)
    float scale = (float)(log(135168.0) / log(1000.0) / 16.0);

    hipLaunchKernelGGL(k_prep, dim3(1120), dim3(256), 0, stream,
                       fc, fcT, Q, WTq, K, WTk, fm, V, vproj);
    hipLaunchKernelGGL(k_proj, dim3(64, 8), dim3(256), 0, stream,
                       WTq, WTk, fcT, qproj, kproj);
    hipLaunchKernelGGL(k_scores, dim3(64, 8), dim3(256), 0, stream,
                       qproj, kproj, kb, scores);
    hipLaunchKernelGGL(k_out, dim3(256), dim3(512), 0, stream,
                       scores, vproj, vb, fm, out, scale);
}